// Round 2
// baseline (223.506 us; speedup 1.0000x reference)
//
#include <hip/hip_runtime.h>
#include <hip/hip_bf16.h>
#include <math.h>

#define B_     16
#define C_     256
#define H_     56
#define W_     56
#define HEADS_ 4
#define CPER_  64
#define R_     16
#define HW_    (H_*W_)      // 3136
#define BN_EPS_ 1e-5f

typedef short bf16x8 __attribute__((ext_vector_type(8)));
typedef float f32x4  __attribute__((ext_vector_type(4)));

__device__ inline unsigned short f2bf(float f) {
    unsigned int u = __builtin_bit_cast(unsigned int, f);
    u += 0x7fffu + ((u >> 16) & 1u);          // RNE (finite inputs only)
    return (unsigned short)(u >> 16);
}

// ---------------- K0: exact fp32 BN+ReLU+mean per (b,c) plane --------------------------
__global__ __launch_bounds__(64) void k_pool(
    const float* __restrict__ x,
    const float* __restrict__ gamma, const float* __restrict__ beta,
    const float* __restrict__ mean,  const float* __restrict__ var,
    float* __restrict__ xavg)
{
    int plane = blockIdx.x;                   // b*256 + c
    int c = plane & (C_ - 1);
    float s = gamma[c] * rsqrtf(var[c] + BN_EPS_);
    float t = fmaf(-mean[c], s, beta[c]);
    const float4* xp = (const float4*)(x + (size_t)plane * HW_);
    float sum = 0.f;
    for (int i = threadIdx.x; i < HW_ / 4; i += 64) {
        float4 v = xp[i];
        sum += fmaxf(fmaf(v.x, s, t), 0.f) + fmaxf(fmaf(v.y, s, t), 0.f)
             + fmaxf(fmaf(v.z, s, t), 0.f) + fmaxf(fmaf(v.w, s, t), 0.f);
    }
    for (int off = 32; off; off >>= 1) sum += __shfl_down(sum, off, 64);
    if (threadIdx.x == 0) xavg[plane] = sum * (1.f / HW_);
}

// ---------------- K2: SE gate, exact rank-k threshold, compaction, lasso ---------------
__global__ __launch_bounds__(256) void k_se(
    const float* __restrict__ xavg,
    const float* __restrict__ fc1, const float* __restrict__ fc2,
    const float* __restrict__ fc2b, const int* __restrict__ kptr,
    float* __restrict__ maskc, int* __restrict__ aidx64,
    int* __restrict__ act_cnt, float* __restrict__ lasso)
{
    int hb = blockIdx.x;              // h*B + b
    int h = hb / B_, b = hb - h * B_;
    int tid = threadIdx.x;            // = channel c

    __shared__ float sav[C_], sy1[R_], smask[C_], sred[4], sthr;
    __shared__ int scnt, s_ord[C_];

    sav[tid] = xavg[b * C_ + tid];
    if (tid == 0) scnt = 0;
    __syncthreads();

    if (tid < R_) {
        const float* w = fc1 + (size_t)(h * R_ + tid) * C_;
        float acc = 0.f;
        for (int c2 = 0; c2 < C_; ++c2) acc = fmaf(sav[c2], w[c2], acc);
        sy1[tid] = fmaxf(acc, 0.f);
    }
    __syncthreads();

    const float* w2 = fc2 + (size_t)(h * C_ + tid) * R_;
    float acc = fc2b[h * C_ + tid];
    for (int r = 0; r < R_; ++r) acc = fmaf(sy1[r], w2[r], acc);
    float m = fmaxf(acc, 0.f);
    smask[tid] = m;
    __syncthreads();

    float ls = m;
    for (int off = 32; off > 0; off >>= 1) ls += __shfl_down(ls, off, 64);
    int lane = tid & 63, wv = tid >> 6;
    if (lane == 0) sred[wv] = ls;

    int cl = 0, ce = 0;
    for (int j = 0; j < C_; ++j) {
        float vj = smask[j];
        cl += (vj < m);
        ce += (vj == m);
    }
    if (tid == 0) sthr = -1e30f;
    __syncthreads();
    int k = kptr[0];
    if (k > 0 && cl <= k - 1 && (k - 1) < cl + ce) sthr = m;
    __syncthreads();

    float thr = sthr;
    float mc = (m <= thr) ? 0.f : m;
    maskc[hb * C_ + tid] = mc;
    if (mc != 0.f) {
        int p = atomicAdd(&scnt, 1);          // order-free (all consumers use same list)
        s_ord[p] = tid;
    }
    __syncthreads();
    if (tid < 64) aidx64[hb * 64 + tid] = (tid < scnt) ? s_ord[tid] : 0;  // zero-padded
    if (tid == 0) {
        act_cnt[hb] = scnt;
        atomicAdd(lasso, (sred[0] + sred[1] + sred[2] + sred[3]) * (1.f / (B_ * C_)));
    }
}

// ---------------- K2c: compact+mask weights -> Wc[hb][t][j][cp] bf16 -------------------
// Reads conv_w DIRECTLY (k_wt2 fused away): the stride-9 gather is paid ONCE here
// instead of once in k_wt2 plus a gathered re-read of wt2f. Plain cp layout (no LDS
// rotation needed any more -- k_conv reads weights straight from L2).
__global__ __launch_bounds__(256) void k_wgather(
    const float* __restrict__ convw, const float* __restrict__ maskc,
    const int* __restrict__ aidx64, const int* __restrict__ acnt,
    short* __restrict__ Wc)
{
    int t = blockIdx.x, hb = blockIdx.y;
    int h = hb >> 4;
    int tid = threadIdx.x;
    int cnt = acnt[hb];
    __shared__ int s_act[64];
    __shared__ float s_mv[64];
    if (tid < 64) {
        int a = aidx64[hb * 64 + tid];
        s_act[tid] = a;
        s_mv[tid]  = (tid < cnt) ? maskc[hb * C_ + a] : 0.f;
    }
    __syncthreads();
    const float* wsrc = convw + (size_t)h * CPER_ * C_ * 9;
    short* wdst = Wc + (size_t)(hb * 9 + t) * (CPER_ * 64);
    for (int it = 0; it < 16; ++it) {
        int e = it * 256 + tid;
        int cp = e & 63, j = e >> 6;
        float v = wsrc[((size_t)j * C_ + s_act[cp]) * 9 + t] * s_mv[cp];  // mask folded in
        wdst[j * 64 + cp] = (short)f2bf(v);
    }
}

// ---------------- K1: BN+ReLU+bf16 DIRECT channel compaction -> xc[hb][px][64] ---------
// thread = (h, slot): BN+ReLU only the ACTIVE channel rows, write LDS [px][h*64+cp]
// with contiguous conflict-free u16 stores, then phase 2 is a pure wide linear copy.
__global__ __launch_bounds__(256) void k_bnc(
    const float* __restrict__ x,
    const float* __restrict__ gamma, const float* __restrict__ beta,
    const float* __restrict__ mean,  const float* __restrict__ var,
    const int* __restrict__ aidx64, short* __restrict__ xc)
{
    int y = blockIdx.x, b = blockIdx.y;
    int tid = threadIdx.x;                    // tid = h*64 + cp
    int h = tid >> 6;
    __shared__ __align__(16) unsigned short T[W_ * 256];   // [px][h*64+cp], 28.7 KB

    int c = aidx64[(h * B_ + b) * 64 + (tid & 63)];        // padded slots -> c=0 (weights are 0)
    float s = gamma[c] * rsqrtf(var[c] + BN_EPS_);
    float t0 = fmaf(-mean[c], s, beta[c]);
    const float* xrow = x + ((size_t)(b * C_ + c)) * HW_ + y * W_;
    #pragma unroll
    for (int f = 0; f < 14; ++f) {
        float4 v = *(const float4*)(xrow + f * 4);
        int px = f * 4;
        T[(px + 0) * 256 + tid] = f2bf(fmaxf(fmaf(v.x, s, t0), 0.f));
        T[(px + 1) * 256 + tid] = f2bf(fmaxf(fmaf(v.y, s, t0), 0.f));
        T[(px + 2) * 256 + tid] = f2bf(fmaxf(fmaf(v.z, s, t0), 0.f));
        T[(px + 3) * 256 + tid] = f2bf(fmaxf(fmaf(v.w, s, t0), 0.f));
    }
    __syncthreads();

    const uint2* Ts = (const uint2*)T;        // 64 uint2 per pixel row
    uint2* ob = (uint2*)xc;
    #pragma unroll
    for (int it = 0; it < 14; ++it) {
        int e = it * 256 + tid;               // e < 3584 = 56px * 64 uint2
        int px = e >> 6, col4 = e & 63;       // col4 = (h*64+cp)/4
        int hh = col4 >> 4, cp4 = col4 & 15;
        uint2 v = Ts[px * 64 + col4];
        ob[((size_t)(hh * B_ + b) * HW_ + (size_t)y * W_ + px) * 16 + cp4] = v;
    }
}

// ---------------- K3: implicit-GEMM bf16 MFMA conv, ZERO LDS, zero barriers ------------
// Weights Wc (73.7 KB/hb, reused by 14 blocks) are L2-resident: A-frags are read
// DIRECTLY from global, like the B-frags. No staging, no barriers -> waves fully
// independent, compiler free to software-pipeline loads across the whole unrolled
// 9-tap body. __launch_bounds__(256,3) gives ~170 unified VGPR+AGPR: the 64-reg
// accumulator plus ~2 clusters of load prefetch fit (the R1 version was capped at
// 128 and had ZERO prefetch headroom -- that was the latency bottleneck).
__global__ __launch_bounds__(256, 3) void k_conv(
    const short* __restrict__ xc, const short* __restrict__ Wc,
    float* __restrict__ out)
{
    int g = blockIdx.x;
    int vx = g & 7, r = g >> 3;               // XCD-local hb window (Wc/xc L2-resident)
    int hb = vx * 8 + r / 14;
    int band = r - (r / 14) * 14;
    int h = hb >> 4, b = hb & 15;
    int tid = threadIdx.x, lane = tid & 63, wv = tid >> 6;
    int m = lane & 15, q = lane >> 4;
    int yrow = band * 4 + wv;

    const short* Wh = Wc + (size_t)hb * 9 * 4096;
    const short* xb = xc + (size_t)hb * HW_ * 64;

    f32x4 acc[4][4];                          // [jt][xt]
    #pragma unroll
    for (int i = 0; i < 4; ++i)
        #pragma unroll
        for (int j = 0; j < 4; ++j)
            #pragma unroll
            for (int rr = 0; rr < 4; ++rr) acc[i][j][rr] = 0.f;

    #pragma unroll
    for (int t = 0; t < 9; ++t) {
        const int dy = t / 3 - 1, dx = t % 3 - 1;
        int gy = yrow + dy;
        bool gyok = (unsigned)gy < (unsigned)H_;
        const short* Wt = Wh + t * 4096;

        #pragma unroll
        for (int c0 = 0; c0 < 64; c0 += 32) {
            bf16x8 aF[4], bF[4];
            #pragma unroll
            for (int jt = 0; jt < 4; ++jt)
                aF[jt] = *(const bf16x8*)(Wt + (jt * 16 + m) * 64 + c0 + q * 8);
            #pragma unroll
            for (int xt = 0; xt < 4; ++xt) {
                int gx = xt * 16 + m + dx;
                bf16x8 v = {0, 0, 0, 0, 0, 0, 0, 0};
                if (gyok && (unsigned)gx < (unsigned)W_)
                    v = *(const bf16x8*)(xb + ((size_t)(gy * W_ + gx)) * 64 + c0 + q * 8);
                bF[xt] = v;
            }
            __builtin_amdgcn_s_setprio(1);
            #pragma unroll
            for (int jt = 0; jt < 4; ++jt)
                #pragma unroll
                for (int xt = 0; xt < 4; ++xt)
                    acc[jt][xt] = __builtin_amdgcn_mfma_f32_16x16x32_bf16(
                        aF[jt], bF[xt], acc[jt][xt], 0, 0, 0);
            __builtin_amdgcn_s_setprio(0);
        }
    }

    #pragma unroll
    for (int xt = 0; xt < 4; ++xt) {
        int xx = xt * 16 + m;
        if (xx < W_) {
            #pragma unroll
            for (int jt = 0; jt < 4; ++jt)
                #pragma unroll
                for (int rr = 0; rr < 4; ++rr) {
                    int j = jt * 16 + q * 4 + rr;         // D: row = quad*4 + reg
                    int oc = j * HEADS_ + h;              // head interleave
                    out[(((size_t)b * C_ + oc) * H_ + yrow) * W_ + xx] = acc[jt][xt][rr];
                }
        }
    }
}

// ---------------- launch ----------------------------------------------------------------
extern "C" void kernel_launch(void* const* d_in, const int* in_sizes, int n_in,
                              void* d_out, int out_size, void* d_ws, size_t ws_size,
                              hipStream_t stream)
{
    const float* x     = (const float*)d_in[0];
    const float* gamma = (const float*)d_in[1];
    const float* beta  = (const float*)d_in[2];
    const float* mean  = (const float*)d_in[3];
    const float* var   = (const float*)d_in[4];
    const float* fc1   = (const float*)d_in[5];
    const float* fc2   = (const float*)d_in[6];
    const float* fc2b  = (const float*)d_in[7];
    const float* convw = (const float*)d_in[8];
    const int*   kptr  = (const int*)d_in[9];

    float* out   = (float*)d_out;
    float* lasso = out + (size_t)B_ * C_ * HW_;

    char* ws = (char*)d_ws;
    size_t off = 0;
    short* xc    = (short*)(ws + off); off += (size_t)HEADS_ * B_ * HW_ * 64 * 2;  // 25.7 MB
    off = (off + 255) & ~(size_t)255;
    float* xavg  = (float*)(ws + off); off += (size_t)B_ * C_ * 4;
    float* maskc = (float*)(ws + off); off += (size_t)HEADS_ * B_ * C_ * 4;
    int*   aidx64= (int*)  (ws + off); off += (size_t)HEADS_ * B_ * 64 * 4;
    int*   acnt  = (int*)  (ws + off); off += (size_t)HEADS_ * B_ * 4;
    off = (off + 255) & ~(size_t)255;
    short* Wc    = (short*)(ws + off); off += (size_t)HEADS_ * B_ * 9 * CPER_ * 64 * 2; // 4.72 MB

    hipMemsetAsync(lasso, 0, 4, stream);

    k_pool<<<B_ * C_, 64, 0, stream>>>(x, gamma, beta, mean, var, xavg);
    k_se<<<HEADS_ * B_, 256, 0, stream>>>(xavg, fc1, fc2, fc2b, kptr,
                                          maskc, aidx64, acnt, lasso);
    k_wgather<<<dim3(9, HEADS_ * B_), 256, 0, stream>>>(convw, maskc, aidx64, acnt, Wc);
    k_bnc<<<dim3(H_, B_), 256, 0, stream>>>(x, gamma, beta, mean, var, aidx64, xc);
    k_conv<<<HEADS_ * B_ * (H_ / 4), 256, 0, stream>>>(xc, Wc, out);
}

// Round 3
// 190.644 us; speedup vs baseline: 1.1724x; 1.1724x over previous
//
#include <hip/hip_runtime.h>
#include <hip/hip_bf16.h>
#include <math.h>

#define B_     16
#define C_     256
#define H_     56
#define W_     56
#define HEADS_ 4
#define CPER_  64
#define R_     16
#define HW_    (H_*W_)      // 3136
#define BN_EPS_ 1e-5f

typedef short bf16x8 __attribute__((ext_vector_type(8)));
typedef float f32x4  __attribute__((ext_vector_type(4)));

__device__ inline unsigned short f2bf(float f) {
    unsigned int u = __builtin_bit_cast(unsigned int, f);
    u += 0x7fffu + ((u >> 16) & 1u);          // RNE (finite inputs only)
    return (unsigned short)(u >> 16);
}

// ---------------- K0: exact fp32 BN+ReLU+mean per (b,c) plane --------------------------
__global__ __launch_bounds__(64) void k_pool(
    const float* __restrict__ x,
    const float* __restrict__ gamma, const float* __restrict__ beta,
    const float* __restrict__ mean,  const float* __restrict__ var,
    float* __restrict__ xavg)
{
    int plane = blockIdx.x;                   // b*256 + c
    int c = plane & (C_ - 1);
    float s = gamma[c] * rsqrtf(var[c] + BN_EPS_);
    float t = fmaf(-mean[c], s, beta[c]);
    const float4* xp = (const float4*)(x + (size_t)plane * HW_);
    float sum = 0.f;
    for (int i = threadIdx.x; i < HW_ / 4; i += 64) {
        float4 v = xp[i];
        sum += fmaxf(fmaf(v.x, s, t), 0.f) + fmaxf(fmaf(v.y, s, t), 0.f)
             + fmaxf(fmaf(v.z, s, t), 0.f) + fmaxf(fmaf(v.w, s, t), 0.f);
    }
    for (int off = 32; off; off >>= 1) sum += __shfl_down(sum, off, 64);
    if (threadIdx.x == 0) xavg[plane] = sum * (1.f / HW_);
}

// ---------------- K2: SE gate, exact rank-k threshold, compaction, lasso ---------------
__global__ __launch_bounds__(256) void k_se(
    const float* __restrict__ xavg,
    const float* __restrict__ fc1, const float* __restrict__ fc2,
    const float* __restrict__ fc2b, const int* __restrict__ kptr,
    float* __restrict__ maskc, int* __restrict__ aidx64,
    int* __restrict__ act_cnt, float* __restrict__ lasso)
{
    int hb = blockIdx.x;              // h*B + b
    int h = hb / B_, b = hb - h * B_;
    int tid = threadIdx.x;            // = channel c

    __shared__ float sav[C_], sy1[R_], smask[C_], sred[4], sthr;
    __shared__ int scnt, s_ord[C_];

    sav[tid] = xavg[b * C_ + tid];
    if (tid == 0) scnt = 0;
    __syncthreads();

    if (tid < R_) {
        const float* w = fc1 + (size_t)(h * R_ + tid) * C_;
        float acc = 0.f;
        for (int c2 = 0; c2 < C_; ++c2) acc = fmaf(sav[c2], w[c2], acc);
        sy1[tid] = fmaxf(acc, 0.f);
    }
    __syncthreads();

    const float* w2 = fc2 + (size_t)(h * C_ + tid) * R_;
    float acc = fc2b[h * C_ + tid];
    for (int r = 0; r < R_; ++r) acc = fmaf(sy1[r], w2[r], acc);
    float m = fmaxf(acc, 0.f);
    smask[tid] = m;
    __syncthreads();

    float ls = m;
    for (int off = 32; off > 0; off >>= 1) ls += __shfl_down(ls, off, 64);
    int lane = tid & 63, wv = tid >> 6;
    if (lane == 0) sred[wv] = ls;

    int cl = 0, ce = 0;
    for (int j = 0; j < C_; ++j) {
        float vj = smask[j];
        cl += (vj < m);
        ce += (vj == m);
    }
    if (tid == 0) sthr = -1e30f;
    __syncthreads();
    int k = kptr[0];
    if (k > 0 && cl <= k - 1 && (k - 1) < cl + ce) sthr = m;
    __syncthreads();

    float thr = sthr;
    float mc = (m <= thr) ? 0.f : m;
    maskc[hb * C_ + tid] = mc;
    if (mc != 0.f) {
        int p = atomicAdd(&scnt, 1);          // order-free (all consumers use same list)
        s_ord[p] = tid;
    }
    __syncthreads();
    if (tid < 64) aidx64[hb * 64 + tid] = (tid < scnt) ? s_ord[tid] : 0;  // zero-padded
    if (tid == 0) {
        act_cnt[hb] = scnt;
        atomicAdd(lasso, (sred[0] + sred[1] + sred[2] + sred[3]) * (1.f / (B_ * C_)));
    }
}

// ---------------- K2c: compact+mask weights -> Wc[hb][t][j][slot] bf16, PRE-ROTATED ----
// Reads conv_w DIRECTLY (stride-9 gather paid once, L2-resident across the 9 t-blocks).
// slot = (cp + 8*(j&7)) & 63 -> k_conv's LDS A-frag ds_read_b128 services all 8
// bank-quads per cycle (0 conflicts, verified R0/R1) and staging writes stay linear.
__global__ __launch_bounds__(256) void k_wgather(
    const float* __restrict__ convw, const float* __restrict__ maskc,
    const int* __restrict__ aidx64, const int* __restrict__ acnt,
    short* __restrict__ Wc)
{
    int t = blockIdx.x, hb = blockIdx.y;
    int h = hb >> 4;
    int tid = threadIdx.x;
    int cnt = acnt[hb];
    __shared__ int s_act[64];
    __shared__ float s_mv[64];
    if (tid < 64) {
        int a = aidx64[hb * 64 + tid];
        s_act[tid] = a;
        s_mv[tid]  = (tid < cnt) ? maskc[hb * C_ + a] : 0.f;
    }
    __syncthreads();
    const float* wsrc = convw + (size_t)h * CPER_ * C_ * 9;
    short* wdst = Wc + (size_t)(hb * 9 + t) * (CPER_ * 64);
    for (int it = 0; it < 16; ++it) {
        int e = it * 256 + tid;
        int cp = e & 63, j = e >> 6;
        float v = wsrc[((size_t)j * C_ + s_act[cp]) * 9 + t] * s_mv[cp];  // mask folded in
        int slot = (cp + 8 * (j & 7)) & 63;              // pre-rotate for LDS bank spread
        wdst[j * 64 + slot] = (short)f2bf(v);
    }
}

// ---------------- K1: BN+ReLU+bf16 DIRECT channel compaction -> xc[hb][px][64] ---------
// thread = (h, slot): BN+ReLU only the ACTIVE channel rows, write LDS [px][h*64+cp]
// with contiguous conflict-free u16 stores, then phase 2 is a pure wide linear copy.
__global__ __launch_bounds__(256) void k_bnc(
    const float* __restrict__ x,
    const float* __restrict__ gamma, const float* __restrict__ beta,
    const float* __restrict__ mean,  const float* __restrict__ var,
    const int* __restrict__ aidx64, short* __restrict__ xc)
{
    int y = blockIdx.x, b = blockIdx.y;
    int tid = threadIdx.x;                    // tid = h*64 + cp
    int h = tid >> 6;
    __shared__ __align__(16) unsigned short T[W_ * 256];   // [px][h*64+cp], 28.7 KB

    int c = aidx64[(h * B_ + b) * 64 + (tid & 63)];        // padded slots -> c=0 (weights are 0)
    float s = gamma[c] * rsqrtf(var[c] + BN_EPS_);
    float t0 = fmaf(-mean[c], s, beta[c]);
    const float* xrow = x + ((size_t)(b * C_ + c)) * HW_ + y * W_;
    #pragma unroll
    for (int f = 0; f < 14; ++f) {
        float4 v = *(const float4*)(xrow + f * 4);
        int px = f * 4;
        T[(px + 0) * 256 + tid] = f2bf(fmaxf(fmaf(v.x, s, t0), 0.f));
        T[(px + 1) * 256 + tid] = f2bf(fmaxf(fmaf(v.y, s, t0), 0.f));
        T[(px + 2) * 256 + tid] = f2bf(fmaxf(fmaf(v.z, s, t0), 0.f));
        T[(px + 3) * 256 + tid] = f2bf(fmaxf(fmaf(v.w, s, t0), 0.f));
    }
    __syncthreads();

    const uint2* Ts = (const uint2*)T;        // 64 uint2 per pixel row
    uint2* ob = (uint2*)xc;
    #pragma unroll
    for (int it = 0; it < 14; ++it) {
        int e = it * 256 + tid;               // e < 3584 = 56px * 64 uint2
        int px = e >> 6, col4 = e & 63;       // col4 = (h*64+cp)/4
        int hh = col4 >> 4, cp4 = col4 & 15;
        uint2 v = Ts[px * 64 + col4];
        ob[((size_t)(hh * B_ + b) * HW_ + (size_t)y * W_ + px) * 16 + cp4] = v;
    }
}

// ---------------- K3: implicit-GEMM bf16 MFMA conv, single-stage LDS, ONE barrier ------
// All 9 taps staged once into 73.7 KB LDS -> after the single __syncthreads the whole
// 288-MFMA / 72-B-load body is straight-line with NO fences (no barriers, NO setprio --
// setprio is a scheduling fence that forced just-in-time loads in R1/R2, VGPR=64/68).
// (256,2): 256-VGPR budget so the compiler can hold many B-frag loads in flight.
// A-frags: rotated-layout ds_read_b128, 0 bank conflicts. B-frags: global, L2-resident
// per-XCD via the hb swizzle.
__global__ __launch_bounds__(256, 2) void k_conv(
    const short* __restrict__ xc, const short* __restrict__ Wc,
    float* __restrict__ out)
{
    int g = blockIdx.x;
    int vx = g & 7, r = g >> 3;               // XCD-local hb window (Wc/xc L2-resident)
    int hb = vx * 8 + r / 14;
    int band = r - (r / 14) * 14;
    int h = hb >> 4, b = hb & 15;
    int tid = threadIdx.x, lane = tid & 63, wv = tid >> 6;
    int m = lane & 15, q = lane >> 4;
    int yrow = band * 4 + wv;

    __shared__ short sW[9 * 4096];            // 73.7 KB, all taps

    const short* Wh = Wc + (size_t)hb * 9 * 4096;
    const short* xb = xc + (size_t)hb * HW_ * 64;

    #pragma unroll
    for (int it = 0; it < 18; ++it) {         // 36864 shorts, 16B/lane coalesced
        int e = it * 256 + tid;
        *(bf16x8*)&sW[e * 8] = *(const bf16x8*)(Wh + e * 8);
    }
    __syncthreads();

    f32x4 acc[4][4];                          // [jt][xt]
    #pragma unroll
    for (int i = 0; i < 4; ++i)
        #pragma unroll
        for (int j = 0; j < 4; ++j)
            #pragma unroll
            for (int rr = 0; rr < 4; ++rr) acc[i][j][rr] = 0.f;

    int arot = q * 8 + 8 * (m & 7);           // A-frag slot rotation (add c0, &63)

    #pragma unroll
    for (int t = 0; t < 9; ++t) {
        const int dy = t / 3 - 1, dx = t % 3 - 1;
        int gy = yrow + dy;
        bool gyok = (unsigned)gy < (unsigned)H_;
        const short* sWc = sW + t * 4096;

        #pragma unroll
        for (int c0 = 0; c0 < 64; c0 += 32) {
            bf16x8 aF[4], bF[4];
            #pragma unroll
            for (int jt = 0; jt < 4; ++jt)
                aF[jt] = *(const bf16x8*)&sWc[(jt * 16 + m) * 64 + ((c0 + arot) & 63)];
            #pragma unroll
            for (int xt = 0; xt < 4; ++xt) {
                int gx = xt * 16 + m + dx;
                bf16x8 v = {0, 0, 0, 0, 0, 0, 0, 0};
                if (gyok && (unsigned)gx < (unsigned)W_)
                    v = *(const bf16x8*)(xb + ((size_t)(gy * W_ + gx)) * 64 + c0 + q * 8);
                bF[xt] = v;
            }
            #pragma unroll
            for (int jt = 0; jt < 4; ++jt)
                #pragma unroll
                for (int xt = 0; xt < 4; ++xt)
                    acc[jt][xt] = __builtin_amdgcn_mfma_f32_16x16x32_bf16(
                        aF[jt], bF[xt], acc[jt][xt], 0, 0, 0);
        }
    }

    #pragma unroll
    for (int xt = 0; xt < 4; ++xt) {
        int xx = xt * 16 + m;
        if (xx < W_) {
            #pragma unroll
            for (int jt = 0; jt < 4; ++jt)
                #pragma unroll
                for (int rr = 0; rr < 4; ++rr) {
                    int j = jt * 16 + q * 4 + rr;         // D: row = quad*4 + reg
                    int oc = j * HEADS_ + h;              // head interleave
                    out[(((size_t)b * C_ + oc) * H_ + yrow) * W_ + xx] = acc[jt][xt][rr];
                }
        }
    }
}

// ---------------- launch ----------------------------------------------------------------
extern "C" void kernel_launch(void* const* d_in, const int* in_sizes, int n_in,
                              void* d_out, int out_size, void* d_ws, size_t ws_size,
                              hipStream_t stream)
{
    const float* x     = (const float*)d_in[0];
    const float* gamma = (const float*)d_in[1];
    const float* beta  = (const float*)d_in[2];
    const float* mean  = (const float*)d_in[3];
    const float* var   = (const float*)d_in[4];
    const float* fc1   = (const float*)d_in[5];
    const float* fc2   = (const float*)d_in[6];
    const float* fc2b  = (const float*)d_in[7];
    const float* convw = (const float*)d_in[8];
    const int*   kptr  = (const int*)d_in[9];

    float* out   = (float*)d_out;
    float* lasso = out + (size_t)B_ * C_ * HW_;

    char* ws = (char*)d_ws;
    size_t off = 0;
    short* xc    = (short*)(ws + off); off += (size_t)HEADS_ * B_ * HW_ * 64 * 2;  // 25.7 MB
    off = (off + 255) & ~(size_t)255;
    float* xavg  = (float*)(ws + off); off += (size_t)B_ * C_ * 4;
    float* maskc = (float*)(ws + off); off += (size_t)HEADS_ * B_ * C_ * 4;
    int*   aidx64= (int*)  (ws + off); off += (size_t)HEADS_ * B_ * 64 * 4;
    int*   acnt  = (int*)  (ws + off); off += (size_t)HEADS_ * B_ * 4;
    off = (off + 255) & ~(size_t)255;
    short* Wc    = (short*)(ws + off); off += (size_t)HEADS_ * B_ * 9 * CPER_ * 64 * 2; // 4.72 MB

    hipMemsetAsync(lasso, 0, 4, stream);

    k_pool<<<B_ * C_, 64, 0, stream>>>(x, gamma, beta, mean, var, xavg);
    k_se<<<HEADS_ * B_, 256, 0, stream>>>(xavg, fc1, fc2, fc2b, kptr,
                                          maskc, aidx64, acnt, lasso);
    k_wgather<<<dim3(9, HEADS_ * B_), 256, 0, stream>>>(convw, maskc, aidx64, acnt, Wc);
    k_bnc<<<dim3(H_, B_), 256, 0, stream>>>(x, gamma, beta, mean, var, aidx64, xc);
    k_conv<<<HEADS_ * B_ * (H_ / 4), 256, 0, stream>>>(xc, Wc, out);
}